// Round 4
// baseline (254.462 us; speedup 1.0000x reference)
//
#include <hip/hip_runtime.h>
#include <cmath>

// DeepFM via constant-weight-matrix MFMA formulation.
// fm = sum_{i<j} W_ij (e_i.e_j) = sum_{t,f} E_tf * (0.5*W' E)_tf, W' symmetric, zero diag.
// G^T = ET @ W'  (A = ET from LDS, B = W' rows from global ws, K-contiguous both)
// deep^T = wdT @ (B from E rows); wide folded into fm epilogue.
// w_ffn: deep [0,3200)=t*32+k | fm [3200,8150)=triu i<j | wide [8150,14550)=t*64+f

#define TS 100
#define F  64
#define FD 32
#define RP 112              // t padded to 7*16
#define KP 128              // t' padded to 4*32 (K dim of fm)
#define OFF_FM 3200
#define OFF_WIDE 8150
#define VOCAB 100000
#define WFM_ELEMS (RP*KP)   // 14336
#define WDT_ELEMS (FD*F)    // 2048

typedef __attribute__((ext_vector_type(8))) short short8;
typedef __attribute__((ext_vector_type(4))) short short4v;
typedef __attribute__((ext_vector_type(4))) float f32x4;

__device__ __forceinline__ ushort f2bf(float x) {       // RN fp32->bf16
    uint u = __float_as_uint(x);
    u = (u + 0x7FFFu + ((u >> 16) & 1u)) >> 16;
    return (ushort)u;
}
__device__ __forceinline__ float bf2f(ushort h) {
    return __uint_as_float((uint)h << 16);
}

// swizzled fragment loads (XOR bits 4-6 by row&7 — G4 bank-conflict fix)
__device__ __forceinline__ short8 ldE(const ushort* base, int row, int kbyte, int lane) {
    int off = (kbyte + ((lane >> 4) << 4)) ^ ((row & 7) << 4);
    return *reinterpret_cast<const short8*>(
        reinterpret_cast<const char*>(base) + row * 128 + off);
}
__device__ __forceinline__ short8 ldET(const ushort* base, int row, int kbyte, int lane) {
    int off = (kbyte + ((lane >> 4) << 4)) ^ ((row & 7) << 4);
    return *reinterpret_cast<const short8*>(
        reinterpret_cast<const char*>(base) + row * 256 + off);
}

__global__ __launch_bounds__(256)
void emb_cvt(const float* __restrict__ src, ushort* __restrict__ dst, int n8) {
    int i = blockIdx.x * 256 + threadIdx.x;
    if (i >= n8) return;
    const float4* s = reinterpret_cast<const float4*>(src) + (size_t)i * 2;
    float4 a = s[0], b = s[1];
    ushort t[8] = { f2bf(a.x), f2bf(a.y), f2bf(a.z), f2bf(a.w),
                    f2bf(b.x), f2bf(b.y), f2bf(b.z), f2bf(b.w) };
    reinterpret_cast<uint4*>(dst)[i] = *reinterpret_cast<const uint4*>(t);
}

// build wfm [112][128] bf16 = 0.5*symmetrized fm weights (zero diag/pad),
// and wdt [32][64] bf16 = w_deep^T
__global__ __launch_bounds__(256)
void prep(const float* __restrict__ w_ffn, const float* __restrict__ w_deep,
          ushort* __restrict__ wfm, ushort* __restrict__ wdt) {
    int j = blockIdx.x * 256 + threadIdx.x;
    if (j < WFM_ELEMS) {
        int t = j >> 7, tp = j & 127;
        ushort v = 0;
        if (t < TS && tp < TS && t != tp) {
            int i = min(t, tp), jj = max(t, tp);
            v = f2bf(0.5f * w_ffn[OFF_FM + i * (199 - i) / 2 + (jj - i - 1)]);
        }
        wfm[j] = v;
    } else if (j < WFM_ELEMS + WDT_ELEMS) {
        int q = j - WFM_ELEMS;
        int k = q >> 6, f = q & 63;
        wdt[q] = f2bf(w_deep[f * FD + k]);
    }
}

template<bool EMBBF>
__global__ __launch_bounds__(256, 4)
void deepfm_main(const int* __restrict__ x,
                 const float* __restrict__ embf,
                 const ushort* __restrict__ embh,
                 const ushort* __restrict__ wfm,
                 const ushort* __restrict__ wdt,
                 const float* __restrict__ b_deep,
                 const float* __restrict__ w_ffn,
                 const float* __restrict__ b_ffn,
                 float* __restrict__ out)
{
    __shared__ ushort Es[RP * F];    // [112][64] bf16, stride 128B, swizzled
    __shared__ ushort ETs[F * KP];   // [64][128] bf16, stride 256B, swizzled
    __shared__ int    xs[TS];
    __shared__ float  red[4];

    const int tid  = threadIdx.x;
    const int b    = blockIdx.x;
    const int lane = tid & 63;
    const int wave = tid >> 6;
    const int lr   = lane & 15;
    const int lg   = lane >> 4;

    if (tid < TS) xs[tid] = x[(size_t)b * TS + tid];
    __syncthreads();

    // gather embedding rows -> Es (row-major, swizzled), zero pad rows
    for (int j = tid; j < RP * 8; j += 256) {
        int r = j >> 3, k8 = j & 7;
        int off = (k8 * 16) ^ ((r & 7) << 4);
        char* dst = reinterpret_cast<char*>(Es) + r * 128 + off;
        if (r < TS) {
            if (EMBBF) {
                *reinterpret_cast<uint4*>(dst) =
                    *reinterpret_cast<const uint4*>(embh + (size_t)xs[r] * F + k8 * 8);
            } else {
                const float* s = embf + (size_t)xs[r] * F + k8 * 8;
                float4 a = reinterpret_cast<const float4*>(s)[0];
                float4 c = reinterpret_cast<const float4*>(s)[1];
                ushort t[8] = { f2bf(a.x), f2bf(a.y), f2bf(a.z), f2bf(a.w),
                                f2bf(c.x), f2bf(c.y), f2bf(c.z), f2bf(c.w) };
                *reinterpret_cast<uint4*>(dst) = *reinterpret_cast<const uint4*>(t);
            }
        } else {
            *reinterpret_cast<uint4*>(dst) = make_uint4(0, 0, 0, 0);
        }
    }
    __syncthreads();

    // LDS transpose: thread (half=tid>>7, r=tid&127) reads E[r] f-half,
    // scatters to ET[f][r]. Writes: lanes r consecutive -> 2 lanes/bank (free).
    {
        int half = tid >> 7, r = tid & 127;
        ushort vals[32];
        if (r < RP) {
            #pragma unroll
            for (int c = 0; c < 4; ++c) {
                int off = (half * 64 + c * 16) ^ ((r & 7) << 4);
                *reinterpret_cast<short8*>(vals + c * 8) =
                    *reinterpret_cast<const short8*>(
                        reinterpret_cast<const char*>(Es) + r * 128 + off);
            }
        } else {
            #pragma unroll
            for (int q = 0; q < 32; ++q) vals[q] = 0;
        }
        #pragma unroll
        for (int q = 0; q < 32; ++q) {
            int f = half * 32 + q;
            int off = (r * 2) ^ ((f & 7) << 4);
            *reinterpret_cast<ushort*>(reinterpret_cast<char*>(ETs) + f * 256 + off) = vals[q];
        }
    }
    __syncthreads();

    float z = 0.f;

    // ---- fm (+ folded wide): G^T = ET @ W'. M-tile = wave (f rows). ----
    short8 A0 = ldET(ETs, wave * 16 + lr, 0,   lane);
    short8 A1 = ldET(ETs, wave * 16 + lr, 64,  lane);
    short8 A2 = ldET(ETs, wave * 16 + lr, 128, lane);
    short8 A3 = ldET(ETs, wave * 16 + lr, 192, lane);
    const int f0 = wave * 16 + lg * 4;
    for (int nt = 0; nt < 7; ++nt) {
        f32x4 acc = {0.f, 0.f, 0.f, 0.f};
        const ushort* bp = wfm + (nt * 16 + lr) * KP + lg * 8;
        short8 B0 = *reinterpret_cast<const short8*>(bp);
        short8 B1 = *reinterpret_cast<const short8*>(bp + 32);
        short8 B2 = *reinterpret_cast<const short8*>(bp + 64);
        short8 B3 = *reinterpret_cast<const short8*>(bp + 96);
        acc = __builtin_amdgcn_mfma_f32_16x16x32_bf16(A0, B0, acc, 0, 0, 0);
        acc = __builtin_amdgcn_mfma_f32_16x16x32_bf16(A1, B1, acc, 0, 0, 0);
        acc = __builtin_amdgcn_mfma_f32_16x16x32_bf16(A2, B2, acc, 0, 0, 0);
        acc = __builtin_amdgcn_mfma_f32_16x16x32_bf16(A3, B3, acc, 0, 0, 0);
        int t = nt * 16 + lr;
        int tc = min(t, TS - 1);
        float4 ww = *reinterpret_cast<const float4*>(w_ffn + OFF_WIDE + tc * F + f0);
        int evoff = (f0 * 2) ^ ((t & 7) << 4);
        short4v ev = *reinterpret_cast<const short4v*>(
            reinterpret_cast<const char*>(Es) + t * 128 + evoff);
        #pragma unroll
        for (int r2 = 0; r2 < 4; ++r2)
            z += bf2f((ushort)ev[r2]) * (acc[r2] + (&ww.x)[r2]);  // E row>=TS is 0
    }

    // ---- deep: D^T = wdT @ (B from E rows). C: col=t, rows=k. ----
    for (int nt = wave; nt < 7; nt += 4) {
        int t = nt * 16 + lr;
        int tc = min(t, TS - 1);
        bool valid = t < TS;
        short8 Bb0 = ldE(Es, t, 0,  lane);
        short8 Bb1 = ldE(Es, t, 64, lane);
        #pragma unroll
        for (int m = 0; m < 2; ++m) {
            f32x4 acc = {0.f, 0.f, 0.f, 0.f};
            const ushort* ap = wdt + (m * 16 + lr) * F + lg * 8;
            short8 Aa0 = *reinterpret_cast<const short8*>(ap);
            short8 Aa1 = *reinterpret_cast<const short8*>(ap + 32);
            acc = __builtin_amdgcn_mfma_f32_16x16x32_bf16(Aa0, Bb0, acc, 0, 0, 0);
            acc = __builtin_amdgcn_mfma_f32_16x16x32_bf16(Aa1, Bb1, acc, 0, 0, 0);
            int k0 = m * 16 + lg * 4;
            float4 wd4 = *reinterpret_cast<const float4*>(w_ffn + tc * FD + k0);
            float4 bd4 = *reinterpret_cast<const float4*>(b_deep + k0);
            #pragma unroll
            for (int r2 = 0; r2 < 4; ++r2) {
                float w = valid ? (&wd4.x)[r2] : 0.f;
                z += fmaxf(acc[r2] + (&bd4.x)[r2], 0.f) * w;
            }
        }
    }

    // ---- block reduce + sigmoid ----
    #pragma unroll
    for (int off = 32; off > 0; off >>= 1) z += __shfl_down(z, off, 64);
    if ((tid & 63) == 0) red[wave] = z;
    __syncthreads();
    if (tid == 0) {
        float t = red[0] + red[1] + red[2] + red[3] + b_ffn[0];
        out[b] = 1.f / (1.f + expf(-t));
    }
}

extern "C" void kernel_launch(void* const* d_in, const int* in_sizes, int n_in,
                              void* d_out, int out_size, void* d_ws, size_t ws_size,
                              hipStream_t stream) {
    const int*   x      = (const int*)  d_in[0];
    const float* emb    = (const float*)d_in[1];
    const float* w_deep = (const float*)d_in[2];
    const float* b_deep = (const float*)d_in[3];
    const float* w_ffn  = (const float*)d_in[4];
    const float* b_ffn  = (const float*)d_in[5];
    float* out = (float*)d_out;
    const int bs = in_sizes[0] / TS;                       // 8192
    const size_t embh_bytes = (size_t)VOCAB * F * 2;       // 12.8 MB
    const size_t w_bytes = (size_t)(WFM_ELEMS + WDT_ELEMS) * 2;  // 32 KB

    if (ws_size >= embh_bytes + w_bytes) {
        ushort* embh = (ushort*)d_ws;
        ushort* wfm  = (ushort*)((char*)d_ws + embh_bytes);
        ushort* wdt  = wfm + WFM_ELEMS;
        const int n8 = VOCAB * F / 8;
        hipLaunchKernelGGL(emb_cvt, dim3((n8 + 255) / 256), dim3(256), 0, stream,
                           emb, embh, n8);
        hipLaunchKernelGGL(prep, dim3(64), dim3(256), 0, stream,
                           w_ffn, w_deep, wfm, wdt);
        hipLaunchKernelGGL((deepfm_main<true>), dim3(bs), dim3(256), 0, stream,
                           x, emb, embh, wfm, wdt, b_deep, w_ffn, b_ffn, out);
    } else {
        ushort* wfm = (ushort*)d_ws;
        ushort* wdt = wfm + WFM_ELEMS;
        hipLaunchKernelGGL(prep, dim3(64), dim3(256), 0, stream,
                           w_ffn, w_deep, wfm, wdt);
        hipLaunchKernelGGL((deepfm_main<false>), dim3(bs), dim3(256), 0, stream,
                           x, emb, (const ushort*)nullptr, wfm, wdt, b_deep, w_ffn, b_ffn, out);
    }
}

// Round 5
// 158.908 us; speedup vs baseline: 1.6013x; 1.6013x over previous
//
#include <hip/hip_runtime.h>
#include <cmath>

// DeepFM R5: R3 all-LDS MFMA structure + prepped weight matrices for
// vectorized epilogues + compile-time tile decode (switch over wave).
// fm: C = E_ti x E_tj^T tiles; z += sum C[i][jc] * W2[jc][i]  (W2 masked i<jc<TS)
// deep: C = E_tt x wdT_kt^T; z += relu(C + b) . W3[k][t]      (W3 masked t<TS)
// wide: direct dot in VALU.
// w_ffn: deep [0,3200)=t*32+k | fm [3200,8150)=triu i<j | wide [8150,14550)=t*64+f

#define TS 100
#define F  64
#define FD 32
#define RP 112
#define OFF_FM 3200
#define OFF_WIDE 8150
#define VOCAB 100000
#define W2_ELEMS (RP*RP)      // [jc:112][i:112] fp32
#define W3_ELEMS (FD*RP)      // [k:32][t:112] fp32
#define WDT_ELEMS (FD*F)      // [k:32][f:64] bf16

typedef __attribute__((ext_vector_type(8))) short short8;
typedef __attribute__((ext_vector_type(4))) float f32x4;

constexpr int FM_TI[28] = {0,0,0,0,0,0,0, 1,1,1,1,1,1, 2,2,2,2,2, 3,3,3,3, 4,4,4, 5,5, 6};
constexpr int FM_TJ[28] = {0,1,2,3,4,5,6, 1,2,3,4,5,6, 2,3,4,5,6, 3,4,5,6, 4,5,6, 5,6, 6};

__device__ __forceinline__ ushort f2bf(float x) {
    uint u = __float_as_uint(x);
    u = (u + 0x7FFFu + ((u >> 16) & 1u)) >> 16;
    return (ushort)u;
}
__device__ __forceinline__ float bf2f(ushort h) {
    return __uint_as_float((uint)h << 16);
}

__global__ __launch_bounds__(256)
void emb_cvt(const float* __restrict__ src, ushort* __restrict__ dst, int n8) {
    int i = blockIdx.x * 256 + threadIdx.x;
    if (i >= n8) return;
    const float4* s = reinterpret_cast<const float4*>(src) + (size_t)i * 2;
    float4 a = s[0], b = s[1];
    ushort t[8] = { f2bf(a.x), f2bf(a.y), f2bf(a.z), f2bf(a.w),
                    f2bf(b.x), f2bf(b.y), f2bf(b.z), f2bf(b.w) };
    reinterpret_cast<uint4*>(dst)[i] = *reinterpret_cast<const uint4*>(t);
}

// W2[jc][i] = (i<jc<TS) ? w_fm[tri(i,jc)] : 0   (fp32)
// W3[k][t]  = (t<TS) ? w_ffn[t*32+k] : 0        (fp32)
// wdt[k][f] = w_deep[f*32+k]                    (bf16)
__global__ __launch_bounds__(256)
void prep(const float* __restrict__ w_ffn, const float* __restrict__ w_deep,
          float* __restrict__ W2, float* __restrict__ W3, ushort* __restrict__ wdt) {
    int j = blockIdx.x * 256 + threadIdx.x;
    if (j < W2_ELEMS) {
        int jc = j / RP, i = j % RP;
        float v = 0.f;
        if (i < jc && jc < TS)
            v = w_ffn[OFF_FM + i * (199 - i) / 2 + (jc - i - 1)];
        W2[j] = v;
    } else if (j < W2_ELEMS + W3_ELEMS) {
        int q = j - W2_ELEMS;
        int k = q / RP, t = q % RP;
        W3[q] = (t < TS) ? w_ffn[t * FD + k] : 0.f;
    } else if (j < W2_ELEMS + W3_ELEMS + WDT_ELEMS) {
        int q = j - W2_ELEMS - W3_ELEMS;
        int k = q >> 6, f = q & 63;
        wdt[q] = f2bf(w_deep[f * FD + k]);
    }
}

// per-wave unit computation, fully unrolled with literal tile indices
template<int W>
__device__ __forceinline__ float units(const char* esp, const char* wdp,
                                       int c0, int c1,
                                       const float* pW2, const float* pW3,
                                       const float* bdl) {
    float z = 0.f;
    #pragma unroll
    for (int u = W; u < 42; u += 4) {
        f32x4 acc = {0.f, 0.f, 0.f, 0.f};
        if (u < 28) {
            const int ti = FM_TI[u], tj = FM_TJ[u];
            short8 a0 = *reinterpret_cast<const short8*>(esp + ti * 2048 + c0);
            short8 a1 = *reinterpret_cast<const short8*>(esp + ti * 2048 + c1);
            short8 b0 = *reinterpret_cast<const short8*>(esp + tj * 2048 + c0);
            short8 b1 = *reinterpret_cast<const short8*>(esp + tj * 2048 + c1);
            acc = __builtin_amdgcn_mfma_f32_16x16x32_bf16(a0, b0, acc, 0, 0, 0);
            acc = __builtin_amdgcn_mfma_f32_16x16x32_bf16(a1, b1, acc, 0, 0, 0);
            float4 w = *reinterpret_cast<const float4*>(pW2 + tj * 1792 + ti * 16);
            z += acc[0] * w.x + acc[1] * w.y + acc[2] * w.z + acc[3] * w.w;
        } else {
            const int v = u - 28, tt = v >> 1, kt = v & 1;
            short8 a0 = *reinterpret_cast<const short8*>(esp + tt * 2048 + c0);
            short8 a1 = *reinterpret_cast<const short8*>(esp + tt * 2048 + c1);
            short8 b0 = *reinterpret_cast<const short8*>(wdp + kt * 2048 + c0);
            short8 b1 = *reinterpret_cast<const short8*>(wdp + kt * 2048 + c1);
            acc = __builtin_amdgcn_mfma_f32_16x16x32_bf16(a0, b0, acc, 0, 0, 0);
            acc = __builtin_amdgcn_mfma_f32_16x16x32_bf16(a1, b1, acc, 0, 0, 0);
            float bk = bdl[kt * 16];
            float4 w = *reinterpret_cast<const float4*>(pW3 + kt * 1792 + tt * 16);
            z += fmaxf(acc[0] + bk, 0.f) * w.x + fmaxf(acc[1] + bk, 0.f) * w.y
               + fmaxf(acc[2] + bk, 0.f) * w.z + fmaxf(acc[3] + bk, 0.f) * w.w;
        }
    }
    return z;
}

template<bool EMBBF>
__global__ __launch_bounds__(256)
void deepfm_main(const int* __restrict__ x,
                 const float* __restrict__ embf,
                 const ushort* __restrict__ embh,
                 const float* __restrict__ W2,
                 const float* __restrict__ W3,
                 const ushort* __restrict__ wdt,
                 const float* __restrict__ b_deep,
                 const float* __restrict__ w_ffn,
                 const float* __restrict__ b_ffn,
                 float* __restrict__ out)
{
    __shared__ ushort Es[RP * F];     // [112] rows x 128B, XOR-swizzled
    __shared__ ushort wdT[FD * F];    // [32] rows x 128B, XOR-swizzled
    __shared__ float  bdeep_lds[FD];
    __shared__ int    xs[TS];
    __shared__ float  red[4];

    const int tid  = threadIdx.x;
    const int b    = blockIdx.x;
    const int lane = tid & 63;
    const int wave = tid >> 6;
    const int lr   = lane & 15;
    const int lg   = lane >> 4;

    if (tid < TS) xs[tid] = x[(size_t)b * TS + tid];
    if (tid < FD) bdeep_lds[tid] = b_deep[tid];
    {   // stage prepped wdt -> LDS (1x16B per thread), swizzled
        int k = tid >> 3, k8 = tid & 7;
        int col = (k8 * 16) ^ ((k & 7) << 4);
        *reinterpret_cast<uint4*>(reinterpret_cast<char*>(wdT) + k * 128 + col)
            = *reinterpret_cast<const uint4*>(wdt + k * F + k8 * 8);
    }
    __syncthreads();

    // gather embedding rows -> Es (swizzled), zero pad rows
    for (int j = tid; j < RP * 8; j += 256) {
        int r = j >> 3, k8 = j & 7;
        int col = (k8 * 16) ^ ((r & 7) << 4);
        char* dst = reinterpret_cast<char*>(Es) + r * 128 + col;
        if (r < TS) {
            if (EMBBF) {
                *reinterpret_cast<uint4*>(dst) =
                    *reinterpret_cast<const uint4*>(embh + (size_t)xs[r] * F + k8 * 8);
            } else {
                const float* s = embf + (size_t)xs[r] * F + k8 * 8;
                float4 a = reinterpret_cast<const float4*>(s)[0];
                float4 c = reinterpret_cast<const float4*>(s)[1];
                ushort t[8] = { f2bf(a.x), f2bf(a.y), f2bf(a.z), f2bf(a.w),
                                f2bf(c.x), f2bf(c.y), f2bf(c.z), f2bf(c.w) };
                *reinterpret_cast<uint4*>(dst) = *reinterpret_cast<const uint4*>(t);
            }
        } else {
            *reinterpret_cast<uint4*>(dst) = make_uint4(0, 0, 0, 0);
        }
    }
    __syncthreads();

    // lane-constant fragment address bases
    const int sw = (lr & 7) << 4;
    const int c0 = (lg * 16) ^ sw;
    const int c1 = (64 + lg * 16) ^ sw;
    const char* esp = reinterpret_cast<const char*>(Es) + lr * 128;
    const char* wdp = reinterpret_cast<const char*>(wdT) + lr * 128;
    const float* pW2 = W2 + lr * RP + lg * 4;
    const float* pW3 = W3 + lr * RP + lg * 4;
    const float* bdl = bdeep_lds + lr;

    float z;
    switch (wave) {
        case 0:  z = units<0>(esp, wdp, c0, c1, pW2, pW3, bdl); break;
        case 1:  z = units<1>(esp, wdp, c0, c1, pW2, pW3, bdl); break;
        case 2:  z = units<2>(esp, wdp, c0, c1, pW2, pW3, bdl); break;
        default: z = units<3>(esp, wdp, c0, c1, pW2, pW3, bdl); break;
    }

    // wide: e_flat . w_wide (800 jobs x 8 elems)
    for (int j = tid; j < TS * 8; j += 256) {
        int t = j >> 3, k8 = j & 7;
        int off = (k8 * 16) ^ ((t & 7) << 4);
        short8 v = *reinterpret_cast<const short8*>(
            reinterpret_cast<const char*>(Es) + t * 128 + off);
        const float2* w = reinterpret_cast<const float2*>(w_ffn + OFF_WIDE + t * F + k8 * 8);
        float2 wa = w[0], wb = w[1], wc = w[2], wd = w[3];
        z += bf2f((ushort)v[0]) * wa.x + bf2f((ushort)v[1]) * wa.y
           + bf2f((ushort)v[2]) * wb.x + bf2f((ushort)v[3]) * wb.y
           + bf2f((ushort)v[4]) * wc.x + bf2f((ushort)v[5]) * wc.y
           + bf2f((ushort)v[6]) * wd.x + bf2f((ushort)v[7]) * wd.y;
    }

    // block reduce + sigmoid
    #pragma unroll
    for (int off = 32; off > 0; off >>= 1) z += __shfl_down(z, off, 64);
    if ((tid & 63) == 0) red[wave] = z;
    __syncthreads();
    if (tid == 0) {
        float t = red[0] + red[1] + red[2] + red[3] + b_ffn[0];
        out[b] = 1.f / (1.f + expf(-t));
    }
}

extern "C" void kernel_launch(void* const* d_in, const int* in_sizes, int n_in,
                              void* d_out, int out_size, void* d_ws, size_t ws_size,
                              hipStream_t stream) {
    const int*   x      = (const int*)  d_in[0];
    const float* emb    = (const float*)d_in[1];
    const float* w_deep = (const float*)d_in[2];
    const float* b_deep = (const float*)d_in[3];
    const float* w_ffn  = (const float*)d_in[4];
    const float* b_ffn  = (const float*)d_in[5];
    float* out = (float*)d_out;
    const int bs = in_sizes[0] / TS;                         // 8192
    const size_t embh_bytes = (size_t)VOCAB * F * 2;         // 12.8 MB
    const size_t w2_bytes = W2_ELEMS * 4;                    // 50176
    const size_t w3_bytes = W3_ELEMS * 4;                    // 14336
    const size_t wdt_bytes = WDT_ELEMS * 2;                  // 4096
    const size_t wtot = w2_bytes + w3_bytes + wdt_bytes;
    const int prep_jobs = W2_ELEMS + W3_ELEMS + WDT_ELEMS;   // 18176

    if (ws_size >= embh_bytes + wtot) {
        ushort* embhp = (ushort*)d_ws;
        float*  W2p   = (float*)((char*)d_ws + embh_bytes);
        float*  W3p   = (float*)((char*)d_ws + embh_bytes + w2_bytes);
        ushort* wdtp  = (ushort*)((char*)d_ws + embh_bytes + w2_bytes + w3_bytes);
        const int n8 = VOCAB * F / 8;
        hipLaunchKernelGGL(emb_cvt, dim3((n8 + 255) / 256), dim3(256), 0, stream,
                           emb, embhp, n8);
        hipLaunchKernelGGL(prep, dim3((prep_jobs + 255) / 256), dim3(256), 0, stream,
                           w_ffn, w_deep, W2p, W3p, wdtp);
        hipLaunchKernelGGL((deepfm_main<true>), dim3(bs), dim3(256), 0, stream,
                           x, emb, embhp, W2p, W3p, wdtp, b_deep, w_ffn, b_ffn, out);
    } else {
        float*  W2p  = (float*)d_ws;
        float*  W3p  = (float*)((char*)d_ws + w2_bytes);
        ushort* wdtp = (ushort*)((char*)d_ws + w2_bytes + w3_bytes);
        hipLaunchKernelGGL(prep, dim3((prep_jobs + 255) / 256), dim3(256), 0, stream,
                           w_ffn, w_deep, W2p, W3p, wdtp);
        hipLaunchKernelGGL((deepfm_main<false>), dim3(bs), dim3(256), 0, stream,
                           x, emb, (const ushort*)nullptr, W2p, W3p, wdtp,
                           b_deep, w_ffn, b_ffn, out);
    }
}